// Round 2
// baseline (224.681 us; speedup 1.0000x reference)
//
#include <hip/hip_runtime.h>

// R2: full bf16-MFMA pipeline.
//  casts -> fused QKV GEMM (bf16 MFMA) -> rope+cast -> V transpose-cast
//        -> flash-causal GQA attention (swapped-QK^T MFMA) -> WO GEMM.
// B=2 S=2048 D=1024 H=16 HKV=4 HD=64 REP=4

#define B_   2
#define S_   2048
#define D_   1024
#define H_   16
#define HKV_ 4
#define HD_  64

typedef __attribute__((ext_vector_type(8))) short bf16x8;
typedef __attribute__((ext_vector_type(4))) float f32x4;
typedef __attribute__((ext_vector_type(4))) short short4v;

__device__ __forceinline__ short f2bf(float f) {
    unsigned u = __builtin_bit_cast(unsigned, f);
    u += 0x7fffu + ((u >> 16) & 1u);      // round-to-nearest-even
    return (short)(u >> 16);
}

// async global->LDS, 16B per lane; dest must be wave-uniform base (lane*16 added by HW)
__device__ __forceinline__ void gll16(const void* g, void* l) {
    __builtin_amdgcn_global_load_lds(
        (const __attribute__((address_space(1))) unsigned int*)g,
        (__attribute__((address_space(3))) unsigned int*)l, 16, 0, 0);
}

// ---------------- fp32 -> bf16 cast (vectorized) ----------------
__global__ void cast_f32_bf16(const float* __restrict__ in, short* __restrict__ out, int n) {
    int i = (blockIdx.x * blockDim.x + threadIdx.x) * 4;
    if (i >= n) return;
    float4 v = *(const float4*)(in + i);
    short4v o = { f2bf(v.x), f2bf(v.y), f2bf(v.z), f2bf(v.w) };
    *(short4v*)(out + i) = o;
}

// ---------------- RoPE + cast: xqkv fp32 cols -> bf16 [b][s][nh][64] ----------------
__global__ void rope_cast(const float* __restrict__ xqkv, short* __restrict__ out,
                          const float* __restrict__ fc, const float* __restrict__ fs,
                          int nh, int colofs) {
    int idx = blockIdx.x * blockDim.x + threadIdx.x;
    int p    = idx & 31;
    int rest = idx >> 5;
    int h    = rest & (nh - 1);           // nh is pow2 (16 or 4)
    int s    = (rest / nh) & (S_ - 1);
    int b    = rest / (nh * S_);
    size_t row = (size_t)b * S_ + s;
    const float* src = xqkv + row * 1536 + colofs + h * 64 + 2 * p;
    float tr = src[0], ti = src[1];
    float c = fc[s * 32 + p], sn = fs[s * 32 + p];
    short* dst = out + (row * nh + h) * 64 + 2 * p;
    dst[0] = f2bf(tr * c - ti * sn);
    dst[1] = f2bf(tr * sn + ti * c);
}

// ---------------- V transpose-cast: xqkv cols 1280.. -> bf16 [b][g][d=64][s=2048] ----------------
__global__ __launch_bounds__(256) void transpose_cast_v(const float* __restrict__ xqkv,
                                                        short* __restrict__ vt) {
    __shared__ float tl[64][65];
    const int t = threadIdx.x;
    const int s0 = blockIdx.x * 64, g = blockIdx.y, b = blockIdx.z;
#pragma unroll
    for (int i = 0; i < 16; ++i) {
        int e = t + i * 256, r = e >> 6, d = e & 63;
        tl[r][d] = xqkv[(size_t)(b * S_ + s0 + r) * 1536 + 1280 + g * 64 + d];
    }
    __syncthreads();
#pragma unroll
    for (int i = 0; i < 16; ++i) {
        int e = t + i * 256, dr = e >> 6, sc = e & 63;
        vt[(size_t)((b * HKV_ + g) * 64 + dr) * S_ + s0 + sc] = f2bf(tl[sc][dr]);
    }
}

// ---------------- bf16 GEMM: C[M,N] = A[M,K] * Bw[N,K]^T, fp32 out ----------------
// 128x128 tile, BK=64, 4 waves (2x2), 16x16x32 MFMA.
// LDS linear dest via global_load_lds; source pre-swizzled (chunk ^= row&7) so
// swizzled ds_read_b128 fragment reads are ~conflict-free (m173/m201 pattern).
__global__ __launch_bounds__(256, 2) void gemm_bf16_nt(
    const short* __restrict__ A, const short* __restrict__ Bw,
    float* __restrict__ C, int N, int K) {
    __shared__ short A_l[128 * 64];
    __shared__ short B_l[128 * 64];
    const int t = threadIdx.x, ln = t & 63, wid = t >> 6;
    const int wr = wid >> 1, wc = wid & 1;
    const int r0 = blockIdx.y * 128, c0 = blockIdx.x * 128;
    f32x4 acc[4][4] = {};
    for (int k0 = 0; k0 < K; k0 += 64) {
#pragma unroll
        for (int i = 0; i < 4; ++i) {
            int row = wid * 32 + i * 8 + (ln >> 3);
            int sc_ = ((ln & 7) ^ (row & 7)) * 8;             // pre-swizzled source chunk
            gll16(A + (size_t)(r0 + row) * K + k0 + sc_, A_l + wid * 2048 + i * 512);
            gll16(Bw + (size_t)(c0 + row) * K + k0 + sc_, B_l + wid * 2048 + i * 512);
        }
        __syncthreads();
#pragma unroll
        for (int kk = 0; kk < 2; ++kk) {
            bf16x8 af[4], bfr[4];
#pragma unroll
            for (int mi = 0; mi < 4; ++mi) {
                int row = wr * 64 + mi * 16 + (ln & 15);
                int addr = row * 128 + (((kk * 4 + (ln >> 4)) ^ (row & 7)) << 4);
                af[mi] = *(const bf16x8*)((const char*)A_l + addr);
            }
#pragma unroll
            for (int ni = 0; ni < 4; ++ni) {
                int col = wc * 64 + ni * 16 + (ln & 15);
                int addr = col * 128 + (((kk * 4 + (ln >> 4)) ^ (col & 7)) << 4);
                bfr[ni] = *(const bf16x8*)((const char*)B_l + addr);
            }
#pragma unroll
            for (int mi = 0; mi < 4; ++mi)
#pragma unroll
                for (int ni = 0; ni < 4; ++ni)
                    acc[mi][ni] = __builtin_amdgcn_mfma_f32_16x16x32_bf16(
                        af[mi], bfr[ni], acc[mi][ni], 0, 0, 0);
        }
        __syncthreads();
    }
    // epilogue: D layout col=ln&15, row=(ln>>4)*4+reg (m89/m91 verified)
#pragma unroll
    for (int mi = 0; mi < 4; ++mi)
#pragma unroll
        for (int ni = 0; ni < 4; ++ni)
#pragma unroll
            for (int rg = 0; rg < 4; ++rg) {
                int r = r0 + wr * 64 + mi * 16 + (ln >> 4) * 4 + rg;
                int c = c0 + wc * 64 + ni * 16 + (ln & 15);
                C[(size_t)r * N + c] = acc[mi][ni][rg];
            }
}

// ---------------- flash-causal GQA attention, bf16 MFMA ----------------
// Block = (q-tile 64, head, batch), 4 waves; wave owns 16 q-rows.
// Swapped QK^T: S^T = mfma(K, Q) so q lives at lane&15 for softmax AND for
// O^T = mfma(V^T, P) accumulation (no cross-lane rescale fixups).
__global__ __launch_bounds__(256, 2) void attn_mfma(
    const short* __restrict__ Qb, const short* __restrict__ Kb,
    const short* __restrict__ Vt, short* __restrict__ Ob) {
    __shared__ short K_l[64 * 64];
    __shared__ short V_l[64 * 64];
    __shared__ short P_l[4 * 16 * 64];   // wave-private 16x64 each
    const int t = threadIdx.x, ln = t & 63, wid = t >> 6;
    const int qt = (int)gridDim.x - 1 - (int)blockIdx.x;   // longest blocks first
    const int h = blockIdx.y, b = blockIdx.z, g = h >> 2;  // REP=4
    const int q0 = qt * 64;
    const int lg = ln >> 4, q = ln & 15;
    const int qrow = q0 + wid * 16 + q;

    bf16x8 qf[2];
#pragma unroll
    for (int kk = 0; kk < 2; ++kk)
        qf[kk] = *(const bf16x8*)(Qb + ((size_t)(b * S_ + qrow) * H_ + h) * HD_ + kk * 32 + lg * 8);

    f32x4 acc[4] = {};
    float mrun = -3.0e38f, lsum = 0.f;

    for (int kt = 0; kt <= qt; ++kt) {
        const int k0 = kt * 64;
#pragma unroll
        for (int i = 0; i < 2; ++i) {     // stage K and V^T tiles (pre-swizzled source)
            int row = wid * 16 + i * 8 + (ln >> 3);
            int sc_ = ((ln & 7) ^ (row & 7)) * 8;
            gll16(Kb + ((size_t)(b * S_ + k0 + row) * HKV_ + g) * HD_ + sc_,
                  K_l + wid * 1024 + i * 512);
            gll16(Vt + ((size_t)((b * HKV_ + g) * 64 + row)) * S_ + k0 + sc_,
                  V_l + wid * 1024 + i * 512);
        }
        __syncthreads();

        f32x4 st[4] = {};                 // S^T[key 64][q 16], key tiles r=0..3
#pragma unroll
        for (int kk = 0; kk < 2; ++kk)
#pragma unroll
            for (int r = 0; r < 4; ++r) {
                int row = r * 16 + q;     // key-in-tile = ln&15
                int addr = row * 128 + (((kk * 4 + lg) ^ (row & 7)) << 4);
                bf16x8 ka = *(const bf16x8*)((const char*)K_l + addr);
                st[r] = __builtin_amdgcn_mfma_f32_16x16x32_bf16(ka, qf[kk], st[r], 0, 0, 0);
            }

        const bool diag = (kt == qt);
        const int qg = q0 + wid * 16 + q;
        float mloc = -3.0e38f;
#pragma unroll
        for (int r = 0; r < 4; ++r)
#pragma unroll
            for (int j = 0; j < 4; ++j) {
                float v = st[r][j] * 0.125f;                       // 1/sqrt(64)
                if (diag && (k0 + r * 16 + lg * 4 + j > qg)) v = -3.0e38f;
                st[r][j] = v;
                mloc = fmaxf(mloc, v);
            }
        mloc = fmaxf(mloc, __shfl_xor(mloc, 16));
        mloc = fmaxf(mloc, __shfl_xor(mloc, 32));
        float nm = fmaxf(mrun, mloc);
        float scl = __expf(mrun - nm);
        float rsum = 0.f;
#pragma unroll
        for (int r = 0; r < 4; ++r)
#pragma unroll
            for (int j = 0; j < 4; ++j) {
                float e = __expf(st[r][j] - nm);
                st[r][j] = e;
                rsum += e;
            }
        rsum += __shfl_xor(rsum, 16);
        rsum += __shfl_xor(rsum, 32);
        lsum = lsum * scl + rsum;
        mrun = nm;
#pragma unroll
        for (int d = 0; d < 4; ++d)
#pragma unroll
            for (int j = 0; j < 4; ++j) acc[d][j] *= scl;

        // P -> wave-private LDS (bf16, swizzled); pre-swizzle byte = q*128 + key*2
#pragma unroll
        for (int r = 0; r < 4; ++r) {
            short4v pk = { f2bf(st[r][0]), f2bf(st[r][1]), f2bf(st[r][2]), f2bf(st[r][3]) };
            int sb = wid * 2048 + q * 128 + ((r * 32 + lg * 8) ^ ((q & 7) << 4));
            *(short4v*)((char*)P_l + sb) = pk;
        }

        // O^T += V^T * P  (D: row=d, col=q=ln&15)
#pragma unroll
        for (int kk2 = 0; kk2 < 2; ++kk2) {
            int pba = wid * 2048 + q * 128 + (((kk2 * 4 + lg) ^ (q & 7)) << 4);
            bf16x8 pb = *(const bf16x8*)((const char*)P_l + pba);
#pragma unroll
            for (int d = 0; d < 4; ++d) {
                int row = d * 16 + q;     // d-in-tile = ln&15
                int addr = row * 128 + (((kk2 * 4 + lg) ^ (row & 7)) << 4);
                bf16x8 va = *(const bf16x8*)((const char*)V_l + addr);
                acc[d] = __builtin_amdgcn_mfma_f32_16x16x32_bf16(va, pb, acc[d], 0, 0, 0);
            }
        }
        __syncthreads();
    }

    float inv = 1.f / lsum;
#pragma unroll
    for (int d = 0; d < 4; ++d) {
        short4v o4 = { f2bf(acc[d][0] * inv), f2bf(acc[d][1] * inv),
                       f2bf(acc[d][2] * inv), f2bf(acc[d][3] * inv) };
        *(short4v*)(Ob + ((size_t)(b * S_ + qrow) * H_ + h) * HD_ + d * 16 + lg * 4) = o4;
    }
}

extern "C" void kernel_launch(void* const* d_in, const int* in_sizes, int n_in,
                              void* d_out, int out_size, void* d_ws, size_t ws_size,
                              hipStream_t stream)
{
    const float* x  = (const float*)d_in[0];
    const float* wq = (const float*)d_in[1];
    const float* wk = (const float*)d_in[2];
    const float* wv = (const float*)d_in[3];
    const float* wo = (const float*)d_in[4];
    const float* fc = (const float*)d_in[5];
    const float* fs = (const float*)d_in[6];
    float* out = (float*)d_out;

    char* ws = (char*)d_ws;
    short* wqkvb = (short*)(ws);                  // [1536][1024] bf16   3.0 MB
    short* wob   = (short*)(ws + 3145728);        // [1024][1024] bf16   2.0 MB
    short* xb    = (short*)(ws + 5242880);        // [4096][1024] bf16   8.0 MB
    float* xqkv  = (float*)(ws + 13631488);       // [4096][1536] f32   24.0 MB
    short* qb    = (short*)(ws + 38797312);       // [b][s][16][64] bf16 8.0 MB
    short* kb    = (short*)(ws + 47185920);       // [b][s][4][64] bf16  2.0 MB
    short* vtb   = (short*)(ws + 49283072);       // [b][4][64][2048]    2.0 MB
    short* aob   = xb;                            // alias: x dead after QKV GEMM

    // casts (wq|wk|wv concatenated row-wise -> one fused QKV weight [1536][1024])
    cast_f32_bf16<<<4096, 256, 0, stream>>>(x,  xb,               4194304);
    cast_f32_bf16<<<1024, 256, 0, stream>>>(wq, wqkvb,            1048576);
    cast_f32_bf16<<<256,  256, 0, stream>>>(wk, wqkvb + 1048576,  262144);
    cast_f32_bf16<<<256,  256, 0, stream>>>(wv, wqkvb + 1310720,  262144);
    cast_f32_bf16<<<1024, 256, 0, stream>>>(wo, wob,              1048576);

    // fused QKV projection: [4096,1536] = xb * wqkvb^T
    gemm_bf16_nt<<<dim3(12, 32), 256, 0, stream>>>(xb, wqkvb, xqkv, 1536, 1024);

    // rope+cast Q,K ; transpose+cast V
    rope_cast<<<8192, 256, 0, stream>>>(xqkv, qb, fc, fs, 16, 0);
    rope_cast<<<2048, 256, 0, stream>>>(xqkv, kb, fc, fs, 4, 1024);
    transpose_cast_v<<<dim3(32, 4, 2), 256, 0, stream>>>(xqkv, vtb);

    // attention -> bf16 [b][s][h][d]
    attn_mfma<<<dim3(32, 16, 2), 256, 0, stream>>>(qb, kb, vtb, aob);

    // output projection: out[4096,1024] = aob * wob^T
    gemm_bf16_nt<<<dim3(8, 32), 256, 0, stream>>>(aob, wob, out, 1024, 1024);
}

// Round 9
// 212.334 us; speedup vs baseline: 1.0581x; 1.0581x over previous
//
#include <hip/hip_runtime.h>

// R9 = R8 resubmitted verbatim (7th acquisition timeout; no code change).
// Merged cast dispatch + fused rope/scale/cast QKV epilogue; attention:
// dbuf K/V, 1 barrier/tile, 4 blocks/CU, exp2 softmax, defer-max THR=8.
// B=2 S=2048 D=1024 H=16 HKV=4 HD=64 REP=4

#define B_   2
#define S_   2048
#define D_   1024
#define H_   16
#define HKV_ 4
#define HD_  64

typedef __attribute__((ext_vector_type(8))) short bf16x8;
typedef __attribute__((ext_vector_type(4))) float f32x4;
typedef __attribute__((ext_vector_type(4))) short short4v;

__device__ __forceinline__ short f2bf(float f) {
    unsigned u = __builtin_bit_cast(unsigned, f);
    u += 0x7fffu + ((u >> 16) & 1u);      // RNE
    return (short)(u >> 16);
}

__device__ __forceinline__ void gll16(const void* g, void* l) {
    __builtin_amdgcn_global_load_lds(
        (const __attribute__((address_space(1))) unsigned int*)g,
        (__attribute__((address_space(3))) unsigned int*)l, 16, 0, 0);
}

// ---------------- merged cast: x|wq|wk|wv|wo -> xb | wqkvb(wq|wk|wv) | wob ----------------
// i4 ranges: [0,1048576) x ; [1048576,1310720) wq ; [1310720,1376256) wk ;
//            [1376256,1441792) wv ; [1441792,1703936) wo.  6656 blocks x 256.
__global__ void cast_all(const float* __restrict__ x,  const float* __restrict__ wq,
                         const float* __restrict__ wk, const float* __restrict__ wv,
                         const float* __restrict__ wo,
                         short* __restrict__ xb, short* __restrict__ wqkvb,
                         short* __restrict__ wob) {
    int i4 = blockIdx.x * blockDim.x + threadIdx.x;
    const float* src;
    short* dst;
    int base;
    if (i4 < 1048576)      { src = x;  dst = xb;    base = 0; }
    else if (i4 < 1310720) { src = wq; dst = wqkvb; base = 1048576; }
    else if (i4 < 1376256) { src = wk; dst = wqkvb + 1048576; base = 1310720; }
    else if (i4 < 1441792) { src = wv; dst = wqkvb + 1310720; base = 1376256; }
    else                   { src = wo; dst = wob;   base = 1441792; }
    int e = (i4 - base) * 4;
    float4 v = *(const float4*)(src + e);
    short4v o = { f2bf(v.x), f2bf(v.y), f2bf(v.z), f2bf(v.w) };
    *(short4v*)(dst + e) = o;
}

// ---------------- QKV GEMM + fused rope/scale/cast epilogue ----------------
__global__ __launch_bounds__(256, 2) void gemm_qkv(
    const short* __restrict__ A, const short* __restrict__ W,
    const float* __restrict__ fc, const float* __restrict__ fs,
    short* __restrict__ qb, short* __restrict__ kb, short* __restrict__ vb) {
    __shared__ short A_l[128 * 64];
    __shared__ short B_l[128 * 64];
    const int t = threadIdx.x, ln = t & 63, wid = t >> 6;
    const int wr = wid >> 1, wc = wid & 1;
    const int r0 = blockIdx.y * 128, c0 = blockIdx.x * 128;
    const int K = 1024;
    f32x4 acc[4][4] = {};
    for (int k0 = 0; k0 < K; k0 += 64) {
#pragma unroll
        for (int i = 0; i < 4; ++i) {
            int row = wid * 32 + i * 8 + (ln >> 3);
            int sc_ = ((ln & 7) ^ (row & 7)) * 8;
            gll16(A + (size_t)(r0 + row) * K + k0 + sc_, A_l + wid * 2048 + i * 512);
            gll16(W + (size_t)(c0 + row) * K + k0 + sc_, B_l + wid * 2048 + i * 512);
        }
        __syncthreads();
#pragma unroll
        for (int kk = 0; kk < 2; ++kk) {
            bf16x8 af[4], bfr[4];
#pragma unroll
            for (int mi = 0; mi < 4; ++mi) {
                int row = wr * 64 + mi * 16 + (ln & 15);
                int addr = row * 128 + (((kk * 4 + (ln >> 4)) ^ (row & 7)) << 4);
                af[mi] = *(const bf16x8*)((const char*)A_l + addr);
            }
#pragma unroll
            for (int ni = 0; ni < 4; ++ni) {
                int col = wc * 64 + ni * 16 + (ln & 15);
                int addr = col * 128 + (((kk * 4 + (ln >> 4)) ^ (col & 7)) << 4);
                bfr[ni] = *(const bf16x8*)((const char*)B_l + addr);
            }
#pragma unroll
            for (int mi = 0; mi < 4; ++mi)
#pragma unroll
                for (int ni = 0; ni < 4; ++ni)
                    acc[mi][ni] = __builtin_amdgcn_mfma_f32_16x16x32_bf16(
                        af[mi], bfr[ni], acc[mi][ni], 0, 0, 0);
        }
        __syncthreads();
    }

    const float QSCALE = 0.18033688f;     // 0.125 * log2(e)
    const int region = (c0 < 1024) ? 0 : (c0 < 1280 ? 1 : 2);   // block-uniform
#pragma unroll
    for (int mi = 0; mi < 4; ++mi)
#pragma unroll
        for (int ni = 0; ni < 4; ++ni) {
            int col = c0 + wc * 64 + ni * 16 + (ln & 15);
#pragma unroll
            for (int rg = 0; rg < 4; ++rg) {
                int row = r0 + wr * 64 + mi * 16 + (ln >> 4) * 4 + rg;
                int s = row & (S_ - 1), b = row >> 11;
                float v = acc[mi][ni][rg];
                if (region == 2) {                       // V: plain cast
                    int cc = col - 1280, g = cc >> 6, d = cc & 63;
                    vb[((size_t)(b * S_ + s) * HKV_ + g) * HD_ + d] = f2bf(v);
                } else {                                 // Q/K: rope
                    int cc = region ? (col - 1024) : col;
                    int d = cc & 63, p = d >> 1;
                    float c = fc[s * 32 + p], sn = fs[s * 32 + p];
                    float pv = __shfl_xor(v, 1);
                    float sgn = (col & 1) ? sn : -sn;
                    float o = v * c + sgn * pv;
                    if (region == 0) {
                        o *= QSCALE;
                        qb[((size_t)(b * S_ + s) * H_ + (cc >> 6)) * HD_ + d] = f2bf(o);
                    } else {
                        kb[((size_t)(b * S_ + s) * HKV_ + (cc >> 6)) * HD_ + d] = f2bf(o);
                    }
                }
            }
        }
}

// ---------------- V transpose: [b][s][g][64] bf16 -> [b][g][64][S] bf16 ----------------
__global__ __launch_bounds__(256) void transpose_v(const short* __restrict__ vb,
                                                   short* __restrict__ vt) {
    __shared__ short tl[64][68];          // 68: 8B-aligned rows + bank-break
    const int t = threadIdx.x;
    const int s0 = blockIdx.x * 64, g = blockIdx.y, b = blockIdx.z;
#pragma unroll
    for (int i = 0; i < 4; ++i) {
        int e = t + i * 256, r = e >> 4, c4 = (e & 15) * 4;
        *(short4v*)&tl[r][c4] =
            *(const short4v*)(vb + ((size_t)(b * S_ + s0 + r) * HKV_ + g) * HD_ + c4);
    }
    __syncthreads();
    const int dr = t >> 2, sc0 = (t & 3) * 16;
#pragma unroll
    for (int i = 0; i < 4; ++i) {
        short4v o = { tl[sc0 + i * 4 + 0][dr], tl[sc0 + i * 4 + 1][dr],
                      tl[sc0 + i * 4 + 2][dr], tl[sc0 + i * 4 + 3][dr] };
        *(short4v*)(vt + ((size_t)((b * HKV_ + g) * 64 + dr)) * S_ + s0 + sc0 + i * 4) = o;
    }
}

// ---------------- WO GEMM (bf16 in, fp32 out) ----------------
__global__ __launch_bounds__(256, 2) void gemm_bf16_nt(
    const short* __restrict__ A, const short* __restrict__ Bw,
    float* __restrict__ C, int N, int K) {
    __shared__ short A_l[128 * 64];
    __shared__ short B_l[128 * 64];
    const int t = threadIdx.x, ln = t & 63, wid = t >> 6;
    const int wr = wid >> 1, wc = wid & 1;
    const int r0 = blockIdx.y * 128, c0 = blockIdx.x * 128;
    f32x4 acc[4][4] = {};
    for (int k0 = 0; k0 < K; k0 += 64) {
#pragma unroll
        for (int i = 0; i < 4; ++i) {
            int row = wid * 32 + i * 8 + (ln >> 3);
            int sc_ = ((ln & 7) ^ (row & 7)) * 8;
            gll16(A + (size_t)(r0 + row) * K + k0 + sc_, A_l + wid * 2048 + i * 512);
            gll16(Bw + (size_t)(c0 + row) * K + k0 + sc_, B_l + wid * 2048 + i * 512);
        }
        __syncthreads();
#pragma unroll
        for (int kk = 0; kk < 2; ++kk) {
            bf16x8 af[4], bfr[4];
#pragma unroll
            for (int mi = 0; mi < 4; ++mi) {
                int row = wr * 64 + mi * 16 + (ln & 15);
                int addr = row * 128 + (((kk * 4 + (ln >> 4)) ^ (row & 7)) << 4);
                af[mi] = *(const bf16x8*)((const char*)A_l + addr);
            }
#pragma unroll
            for (int ni = 0; ni < 4; ++ni) {
                int col = wc * 64 + ni * 16 + (ln & 15);
                int addr = col * 128 + (((kk * 4 + (ln >> 4)) ^ (col & 7)) << 4);
                bfr[ni] = *(const bf16x8*)((const char*)B_l + addr);
            }
#pragma unroll
            for (int mi = 0; mi < 4; ++mi)
#pragma unroll
                for (int ni = 0; ni < 4; ++ni)
                    acc[mi][ni] = __builtin_amdgcn_mfma_f32_16x16x32_bf16(
                        af[mi], bfr[ni], acc[mi][ni], 0, 0, 0);
        }
        __syncthreads();
    }
#pragma unroll
    for (int mi = 0; mi < 4; ++mi)
#pragma unroll
        for (int ni = 0; ni < 4; ++ni)
#pragma unroll
            for (int rg = 0; rg < 4; ++rg) {
                int r = r0 + wr * 64 + mi * 16 + (ln >> 4) * 4 + rg;
                int c = c0 + wc * 64 + ni * 16 + (ln & 15);
                C[(size_t)r * N + c] = acc[mi][ni][rg];
            }
}

// ---------------- flash-causal GQA attention ----------------
// 64-q blocks (4 waves x 16 q-rows), KV tile 64, double-buffered K/V,
// ONE barrier per tile. Q pre-scaled by 0.125*log2e -> exp2 softmax.
__global__ __launch_bounds__(256, 4) void attn_mfma(
    const short* __restrict__ Qb, const short* __restrict__ Kb,
    const short* __restrict__ Vt, short* __restrict__ Ob) {
    __shared__ short K_l[2][64 * 64];
    __shared__ short V_l[2][64 * 64];
    __shared__ short P_l[4][16 * 64];
    const int t = threadIdx.x, ln = t & 63, wid = t >> 6;
    const int qt = (int)gridDim.x - 1 - (int)blockIdx.x;   // longest first
    const int h = blockIdx.y, b = blockIdx.z, g = h >> 2;
    const int q0 = qt * 64;
    const int lg = ln >> 4, q = ln & 15;
    const int qrow = q0 + wid * 16 + q;
    const int stg_row = wid * 16 + (ln >> 3);
    const int stg_sc0 = (ln & 7) * 8;

    bf16x8 qf[2];
#pragma unroll
    for (int kk = 0; kk < 2; ++kk)
        qf[kk] = *(const bf16x8*)(Qb + ((size_t)(b * S_ + qrow) * H_ + h) * HD_ + kk * 32 + lg * 8);

    f32x4 acc[4] = {};
    float mrun = -3.0e38f, lsum = 0.f;

#define STAGE(KT, BUF)                                                              \
    {                                                                               \
        const int k0s = (KT) * 64;                                                  \
        _Pragma("unroll")                                                           \
        for (int i = 0; i < 2; ++i) {                                               \
            int row = stg_row + i * 8;                                              \
            int sc_ = stg_sc0 ^ ((row & 7) * 8);                                    \
            gll16(Kb + ((size_t)(b * S_ + k0s + row) * HKV_ + g) * HD_ + sc_,       \
                  &K_l[BUF][wid * 1024 + i * 512]);                                 \
            gll16(Vt + ((size_t)((b * HKV_ + g) * 64 + row)) * S_ + k0s + sc_,      \
                  &V_l[BUF][wid * 1024 + i * 512]);                                 \
        }                                                                           \
    }

    STAGE(0, 0);
    __syncthreads();
    int cur = 0;

    for (int kt = 0; kt <= qt; ++kt) {
        if (kt < qt) STAGE(kt + 1, cur ^ 1);

        const int k0 = kt * 64;
        f32x4 st[4] = {};
#pragma unroll
        for (int kk = 0; kk < 2; ++kk)
#pragma unroll
            for (int r = 0; r < 4; ++r) {
                int row = r * 16 + q;
                int addr = row * 128 + (((kk * 4 + lg) ^ (row & 7)) << 4);
                bf16x8 ka = *(const bf16x8*)((const char*)&K_l[cur][0] + addr);
                st[r] = __builtin_amdgcn_mfma_f32_16x16x32_bf16(ka, qf[kk], st[r], 0, 0, 0);
            }

        const bool diag = (kt == qt);
        float mloc = -3.0e38f;
        if (diag) {
#pragma unroll
            for (int r = 0; r < 4; ++r)
#pragma unroll
                for (int j = 0; j < 4; ++j) {
                    if (k0 + r * 16 + lg * 4 + j > qrow) st[r][j] = -3.0e38f;
                    mloc = fmaxf(mloc, st[r][j]);
                }
        } else {
#pragma unroll
            for (int r = 0; r < 4; ++r)
#pragma unroll
                for (int j = 0; j < 4; ++j) mloc = fmaxf(mloc, st[r][j]);
        }
        mloc = fmaxf(mloc, __shfl_xor(mloc, 16));
        mloc = fmaxf(mloc, __shfl_xor(mloc, 32));

        if (!__all(mloc <= mrun + 8.f)) {               // defer-max (T13)
            float nm = fmaxf(mrun, mloc);
            float scl = __builtin_amdgcn_exp2f(mrun - nm);
            lsum *= scl;
#pragma unroll
            for (int d = 0; d < 4; ++d)
#pragma unroll
                for (int j = 0; j < 4; ++j) acc[d][j] *= scl;
            mrun = nm;
        }

        float rsum = 0.f;
#pragma unroll
        for (int r = 0; r < 4; ++r)
#pragma unroll
            for (int j = 0; j < 4; ++j) {
                float e = __builtin_amdgcn_exp2f(st[r][j] - mrun);
                st[r][j] = e;
                rsum += e;
            }
        rsum += __shfl_xor(rsum, 16);
        rsum += __shfl_xor(rsum, 32);
        lsum += rsum;

#pragma unroll
        for (int r = 0; r < 4; ++r) {
            short4v pk = { f2bf(st[r][0]), f2bf(st[r][1]), f2bf(st[r][2]), f2bf(st[r][3]) };
            int sb = q * 128 + ((r * 32 + lg * 8) ^ ((q & 7) << 4));
            *(short4v*)((char*)&P_l[wid][0] + sb) = pk;
        }

#pragma unroll
        for (int kk2 = 0; kk2 < 2; ++kk2) {
            int pba = q * 128 + (((kk2 * 4 + lg) ^ (q & 7)) << 4);
            bf16x8 pb = *(const bf16x8*)((const char*)&P_l[wid][0] + pba);
#pragma unroll
            for (int d = 0; d < 4; ++d) {
                int row = d * 16 + q;
                int addr = row * 128 + (((kk2 * 4 + lg) ^ (row & 7)) << 4);
                bf16x8 va = *(const bf16x8*)((const char*)&V_l[cur][0] + addr);
                acc[d] = __builtin_amdgcn_mfma_f32_16x16x32_bf16(va, pb, acc[d], 0, 0, 0);
            }
        }
        __syncthreads();                                 // drains staging vmcnt too
        cur ^= 1;
    }
#undef STAGE

    float inv = 1.f / lsum;
#pragma unroll
    for (int d = 0; d < 4; ++d) {
        short4v o4 = { f2bf(acc[d][0] * inv), f2bf(acc[d][1] * inv),
                       f2bf(acc[d][2] * inv), f2bf(acc[d][3] * inv) };
        *(short4v*)(Ob + ((size_t)(b * S_ + qrow) * H_ + h) * HD_ + d * 16 + lg * 4) = o4;
    }
}

extern "C" void kernel_launch(void* const* d_in, const int* in_sizes, int n_in,
                              void* d_out, int out_size, void* d_ws, size_t ws_size,
                              hipStream_t stream)
{
    const float* x  = (const float*)d_in[0];
    const float* wq = (const float*)d_in[1];
    const float* wk = (const float*)d_in[2];
    const float* wv = (const float*)d_in[3];
    const float* wo = (const float*)d_in[4];
    const float* fc = (const float*)d_in[5];
    const float* fs = (const float*)d_in[6];
    float* out = (float*)d_out;

    char* ws = (char*)d_ws;
    short* wqkvb = (short*)(ws);                  // 1536*1024 bf16  3.0 MB
    short* wob   = (short*)(ws + 3145728);        // 1024*1024 bf16  2.0 MB
    short* xb    = (short*)(ws + 5242880);        // 4096*1024 bf16  8.0 MB
    short* qb    = (short*)(ws + 13631488);       // [b][s][16][64]  8.0 MB
    short* kb    = (short*)(ws + 22020096);       // [b][s][4][64]   2.0 MB
    short* vb    = (short*)(ws + 24117248);       // [b][s][4][64]   2.0 MB
    short* vtb   = (short*)(ws + 26214400);       // [b][4][64][S]   2.0 MB
    short* aob   = xb;                            // alias: x dead after QKV GEMM

    cast_all<<<6656, 256, 0, stream>>>(x, wq, wk, wv, wo, xb, wqkvb, wob);

    gemm_qkv<<<dim3(12, 32), 256, 0, stream>>>(xb, wqkvb, fc, fs, qb, kb, vb);

    transpose_v<<<dim3(32, 4, 2), 256, 0, stream>>>(vb, vtb);

    attn_mfma<<<dim3(32, 16, 2), 256, 0, stream>>>(qb, kb, vtb, aob);

    gemm_bf16_nt<<<dim3(8, 32), 256, 0, stream>>>(aob, wob, out, 1024, 1024);
}

// Round 14
// 196.826 us; speedup vs baseline: 1.1415x; 1.0788x over previous
//
#include <hip/hip_runtime.h>

// R14 = R10 resubmitted verbatim (5th submission; container failed at infra
// level R13; crash-vector audit clean). Paired q-tiles (jp, 31-jp) per 8-wave
// block => uniform 33 tile-steps/block; K staged by waves 0-3, V^T by 4-7.
// Rest identical to R8 (measured 212.3 us, attn 68.2).
// B=2 S=2048 D=1024 H=16 HKV=4 HD=64 REP=4

#define B_   2
#define S_   2048
#define D_   1024
#define H_   16
#define HKV_ 4
#define HD_  64

typedef __attribute__((ext_vector_type(8))) short bf16x8;
typedef __attribute__((ext_vector_type(4))) float f32x4;
typedef __attribute__((ext_vector_type(4))) short short4v;

__device__ __forceinline__ short f2bf(float f) {
    unsigned u = __builtin_bit_cast(unsigned, f);
    u += 0x7fffu + ((u >> 16) & 1u);      // RNE
    return (short)(u >> 16);
}

__device__ __forceinline__ void gll16(const void* g, void* l) {
    __builtin_amdgcn_global_load_lds(
        (const __attribute__((address_space(1))) unsigned int*)g,
        (__attribute__((address_space(3))) unsigned int*)l, 16, 0, 0);
}

// ---------------- merged cast: x|wq|wk|wv|wo -> xb | wqkvb(wq|wk|wv) | wob ----------------
__global__ void cast_all(const float* __restrict__ x,  const float* __restrict__ wq,
                         const float* __restrict__ wk, const float* __restrict__ wv,
                         const float* __restrict__ wo,
                         short* __restrict__ xb, short* __restrict__ wqkvb,
                         short* __restrict__ wob) {
    int i4 = blockIdx.x * blockDim.x + threadIdx.x;
    const float* src;
    short* dst;
    int base;
    if (i4 < 1048576)      { src = x;  dst = xb;    base = 0; }
    else if (i4 < 1310720) { src = wq; dst = wqkvb; base = 1048576; }
    else if (i4 < 1376256) { src = wk; dst = wqkvb + 1048576; base = 1310720; }
    else if (i4 < 1441792) { src = wv; dst = wqkvb + 1310720; base = 1376256; }
    else                   { src = wo; dst = wob;   base = 1441792; }
    int e = (i4 - base) * 4;
    float4 v = *(const float4*)(src + e);
    short4v o = { f2bf(v.x), f2bf(v.y), f2bf(v.z), f2bf(v.w) };
    *(short4v*)(dst + e) = o;
}

// ---------------- QKV GEMM + fused rope/scale/cast epilogue ----------------
__global__ __launch_bounds__(256, 2) void gemm_qkv(
    const short* __restrict__ A, const short* __restrict__ W,
    const float* __restrict__ fc, const float* __restrict__ fs,
    short* __restrict__ qb, short* __restrict__ kb, short* __restrict__ vb) {
    __shared__ short A_l[128 * 64];
    __shared__ short B_l[128 * 64];
    const int t = threadIdx.x, ln = t & 63, wid = t >> 6;
    const int wr = wid >> 1, wc = wid & 1;
    const int r0 = blockIdx.y * 128, c0 = blockIdx.x * 128;
    const int K = 1024;
    f32x4 acc[4][4] = {};
    for (int k0 = 0; k0 < K; k0 += 64) {
#pragma unroll
        for (int i = 0; i < 4; ++i) {
            int row = wid * 32 + i * 8 + (ln >> 3);
            int sc_ = ((ln & 7) ^ (row & 7)) * 8;
            gll16(A + (size_t)(r0 + row) * K + k0 + sc_, A_l + wid * 2048 + i * 512);
            gll16(W + (size_t)(c0 + row) * K + k0 + sc_, B_l + wid * 2048 + i * 512);
        }
        __syncthreads();
#pragma unroll
        for (int kk = 0; kk < 2; ++kk) {
            bf16x8 af[4], bfr[4];
#pragma unroll
            for (int mi = 0; mi < 4; ++mi) {
                int row = wr * 64 + mi * 16 + (ln & 15);
                int addr = row * 128 + (((kk * 4 + (ln >> 4)) ^ (row & 7)) << 4);
                af[mi] = *(const bf16x8*)((const char*)A_l + addr);
            }
#pragma unroll
            for (int ni = 0; ni < 4; ++ni) {
                int col = wc * 64 + ni * 16 + (ln & 15);
                int addr = col * 128 + (((kk * 4 + (ln >> 4)) ^ (col & 7)) << 4);
                bfr[ni] = *(const bf16x8*)((const char*)B_l + addr);
            }
#pragma unroll
            for (int mi = 0; mi < 4; ++mi)
#pragma unroll
                for (int ni = 0; ni < 4; ++ni)
                    acc[mi][ni] = __builtin_amdgcn_mfma_f32_16x16x32_bf16(
                        af[mi], bfr[ni], acc[mi][ni], 0, 0, 0);
        }
        __syncthreads();
    }

    const float QSCALE = 0.18033688f;     // 0.125 * log2(e)
    const int region = (c0 < 1024) ? 0 : (c0 < 1280 ? 1 : 2);   // block-uniform
#pragma unroll
    for (int mi = 0; mi < 4; ++mi)
#pragma unroll
        for (int ni = 0; ni < 4; ++ni) {
            int col = c0 + wc * 64 + ni * 16 + (ln & 15);
#pragma unroll
            for (int rg = 0; rg < 4; ++rg) {
                int row = r0 + wr * 64 + mi * 16 + (ln >> 4) * 4 + rg;
                int s = row & (S_ - 1), b = row >> 11;
                float v = acc[mi][ni][rg];
                if (region == 2) {                       // V: plain cast
                    int cc = col - 1280, g = cc >> 6, d = cc & 63;
                    vb[((size_t)(b * S_ + s) * HKV_ + g) * HD_ + d] = f2bf(v);
                } else {                                 // Q/K: rope
                    int cc = region ? (col - 1024) : col;
                    int d = cc & 63, p = d >> 1;
                    float c = fc[s * 32 + p], sn = fs[s * 32 + p];
                    float pv = __shfl_xor(v, 1);
                    float sgn = (col & 1) ? sn : -sn;
                    float o = v * c + sgn * pv;
                    if (region == 0) {
                        o *= QSCALE;
                        qb[((size_t)(b * S_ + s) * H_ + (cc >> 6)) * HD_ + d] = f2bf(o);
                    } else {
                        kb[((size_t)(b * S_ + s) * HKV_ + (cc >> 6)) * HD_ + d] = f2bf(o);
                    }
                }
            }
        }
}

// ---------------- V transpose: [b][s][g][64] bf16 -> [b][g][64][S] bf16 ----------------
__global__ __launch_bounds__(256) void transpose_v(const short* __restrict__ vb,
                                                   short* __restrict__ vt) {
    __shared__ short tl[64][68];          // 68: 8B-aligned rows + bank-break
    const int t = threadIdx.x;
    const int s0 = blockIdx.x * 64, g = blockIdx.y, b = blockIdx.z;
#pragma unroll
    for (int i = 0; i < 4; ++i) {
        int e = t + i * 256, r = e >> 4, c4 = (e & 15) * 4;
        *(short4v*)&tl[r][c4] =
            *(const short4v*)(vb + ((size_t)(b * S_ + s0 + r) * HKV_ + g) * HD_ + c4);
    }
    __syncthreads();
    const int dr = t >> 2, sc0 = (t & 3) * 16;
#pragma unroll
    for (int i = 0; i < 4; ++i) {
        short4v o = { tl[sc0 + i * 4 + 0][dr], tl[sc0 + i * 4 + 1][dr],
                      tl[sc0 + i * 4 + 2][dr], tl[sc0 + i * 4 + 3][dr] };
        *(short4v*)(vt + ((size_t)((b * HKV_ + g) * 64 + dr)) * S_ + s0 + sc0 + i * 4) = o;
    }
}

// ---------------- WO GEMM (bf16 in, fp32 out) ----------------
__global__ __launch_bounds__(256, 2) void gemm_bf16_nt(
    const short* __restrict__ A, const short* __restrict__ Bw,
    float* __restrict__ C, int N, int K) {
    __shared__ short A_l[128 * 64];
    __shared__ short B_l[128 * 64];
    const int t = threadIdx.x, ln = t & 63, wid = t >> 6;
    const int wr = wid >> 1, wc = wid & 1;
    const int r0 = blockIdx.y * 128, c0 = blockIdx.x * 128;
    f32x4 acc[4][4] = {};
    for (int k0 = 0; k0 < K; k0 += 64) {
#pragma unroll
        for (int i = 0; i < 4; ++i) {
            int row = wid * 32 + i * 8 + (ln >> 3);
            int sc_ = ((ln & 7) ^ (row & 7)) * 8;
            gll16(A + (size_t)(r0 + row) * K + k0 + sc_, A_l + wid * 2048 + i * 512);
            gll16(Bw + (size_t)(c0 + row) * K + k0 + sc_, B_l + wid * 2048 + i * 512);
        }
        __syncthreads();
#pragma unroll
        for (int kk = 0; kk < 2; ++kk) {
            bf16x8 af[4], bfr[4];
#pragma unroll
            for (int mi = 0; mi < 4; ++mi) {
                int row = wr * 64 + mi * 16 + (ln & 15);
                int addr = row * 128 + (((kk * 4 + (ln >> 4)) ^ (row & 7)) << 4);
                af[mi] = *(const bf16x8*)((const char*)A_l + addr);
            }
#pragma unroll
            for (int ni = 0; ni < 4; ++ni) {
                int col = wc * 64 + ni * 16 + (ln & 15);
                int addr = col * 128 + (((kk * 4 + (ln >> 4)) ^ (col & 7)) << 4);
                bfr[ni] = *(const bf16x8*)((const char*)B_l + addr);
            }
#pragma unroll
            for (int mi = 0; mi < 4; ++mi)
#pragma unroll
                for (int ni = 0; ni < 4; ++ni)
                    acc[mi][ni] = __builtin_amdgcn_mfma_f32_16x16x32_bf16(
                        af[mi], bfr[ni], acc[mi][ni], 0, 0, 0);
        }
        __syncthreads();
    }
#pragma unroll
    for (int mi = 0; mi < 4; ++mi)
#pragma unroll
        for (int ni = 0; ni < 4; ++ni)
#pragma unroll
            for (int rg = 0; rg < 4; ++rg) {
                int r = r0 + wr * 64 + mi * 16 + (ln >> 4) * 4 + rg;
                int c = c0 + wc * 64 + ni * 16 + (ln & 15);
                C[(size_t)r * N + c] = acc[mi][ni][rg];
            }
}

// ---------------- flash-causal GQA attention, PAIRED q-tiles ----------------
// Block = (pair jp, head, batch), 8 waves / 512 threads.
// Waves 0-3: q-tile jp (jp+1 k-tiles); waves 4-7: q-tile 31-jp (32-jp k-tiles);
// every block = exactly 33 tile-steps -> uniform makespan, 512 blocks = 2/CU.
// K staged by waves 0-3, V^T by waves 4-7 (shared by both halves).
__global__ __launch_bounds__(512, 4) void attn_mfma(
    const short* __restrict__ Qb, const short* __restrict__ Kb,
    const short* __restrict__ Vt, short* __restrict__ Ob) {
    __shared__ short K_l[2][64 * 64];
    __shared__ short V_l[2][64 * 64];
    __shared__ short P_l[8][16 * 64];
    const int t = threadIdx.x, ln = t & 63, wid = t >> 6;   // wid 0..7
    const int jp = blockIdx.x;                              // 0..15
    const int h = blockIdx.y, b = blockIdx.z, g = h >> 2;
    const int half = wid >> 2;                              // 0: qt=jp, 1: qt=31-jp
    const int wl = wid & 3;
    const int myqt = half ? (31 - jp) : jp;
    const int qtB = 31 - jp;                                // loop bound (>= myqt)
    const int q0 = myqt * 64;
    const int lg = ln >> 4, q = ln & 15;
    const int qrow = q0 + wl * 16 + q;
    const int stg_row = wl * 16 + (ln >> 3);                // 16 rows per wave
    const int stg_sc0 = (ln & 7) * 8;

    bf16x8 qf[2];
#pragma unroll
    for (int kk = 0; kk < 2; ++kk)
        qf[kk] = *(const bf16x8*)(Qb + ((size_t)(b * S_ + qrow) * H_ + h) * HD_ + kk * 32 + lg * 8);

    f32x4 acc[4] = {};
    float mrun = -3.0e38f, lsum = 0.f;

    // waves 0-3 stage K rows, waves 4-7 stage V^T rows (half is wave-uniform)
#define STAGE(KT, BUF)                                                              \
    {                                                                               \
        const int k0s = (KT) * 64;                                                  \
        _Pragma("unroll")                                                           \
        for (int i = 0; i < 2; ++i) {                                               \
            int row = stg_row + i * 8;                                              \
            int sc_ = stg_sc0 ^ ((row & 7) * 8);                                    \
            if (half == 0)                                                          \
                gll16(Kb + ((size_t)(b * S_ + k0s + row) * HKV_ + g) * HD_ + sc_,   \
                      &K_l[BUF][wl * 1024 + i * 512]);                              \
            else                                                                    \
                gll16(Vt + ((size_t)((b * HKV_ + g) * 64 + row)) * S_ + k0s + sc_,  \
                      &V_l[BUF][wl * 1024 + i * 512]);                              \
        }                                                                           \
    }

    STAGE(0, 0);
    __syncthreads();
    int cur = 0;

    for (int kt = 0; kt <= qtB; ++kt) {
        if (kt < qtB) STAGE(kt + 1, cur ^ 1);

        if (kt <= myqt) {                                   // wave-uniform
            const int k0 = kt * 64;
            f32x4 st[4] = {};
#pragma unroll
            for (int kk = 0; kk < 2; ++kk)
#pragma unroll
                for (int r = 0; r < 4; ++r) {
                    int row = r * 16 + q;
                    int addr = row * 128 + (((kk * 4 + lg) ^ (row & 7)) << 4);
                    bf16x8 ka = *(const bf16x8*)((const char*)&K_l[cur][0] + addr);
                    st[r] = __builtin_amdgcn_mfma_f32_16x16x32_bf16(ka, qf[kk], st[r], 0, 0, 0);
                }

            const bool diag = (kt == myqt);
            float mloc = -3.0e38f;
            if (diag) {
#pragma unroll
                for (int r = 0; r < 4; ++r)
#pragma unroll
                    for (int j = 0; j < 4; ++j) {
                        if (k0 + r * 16 + lg * 4 + j > qrow) st[r][j] = -3.0e38f;
                        mloc = fmaxf(mloc, st[r][j]);
                    }
            } else {
#pragma unroll
                for (int r = 0; r < 4; ++r)
#pragma unroll
                    for (int j = 0; j < 4; ++j) mloc = fmaxf(mloc, st[r][j]);
            }
            mloc = fmaxf(mloc, __shfl_xor(mloc, 16));
            mloc = fmaxf(mloc, __shfl_xor(mloc, 32));

            if (!__all(mloc <= mrun + 8.f)) {               // defer-max (T13)
                float nm = fmaxf(mrun, mloc);
                float scl = __builtin_amdgcn_exp2f(mrun - nm);
                lsum *= scl;
#pragma unroll
                for (int d = 0; d < 4; ++d)
#pragma unroll
                    for (int j = 0; j < 4; ++j) acc[d][j] *= scl;
                mrun = nm;
            }

            float rsum = 0.f;
#pragma unroll
            for (int r = 0; r < 4; ++r)
#pragma unroll
                for (int j = 0; j < 4; ++j) {
                    float e = __builtin_amdgcn_exp2f(st[r][j] - mrun);
                    st[r][j] = e;
                    rsum += e;
                }
            rsum += __shfl_xor(rsum, 16);
            rsum += __shfl_xor(rsum, 32);
            lsum += rsum;

#pragma unroll
            for (int r = 0; r < 4; ++r) {
                short4v pk = { f2bf(st[r][0]), f2bf(st[r][1]), f2bf(st[r][2]), f2bf(st[r][3]) };
                int sb = q * 128 + ((r * 32 + lg * 8) ^ ((q & 7) << 4));
                *(short4v*)((char*)&P_l[wid][0] + sb) = pk;
            }

#pragma unroll
            for (int kk2 = 0; kk2 < 2; ++kk2) {
                int pba = q * 128 + (((kk2 * 4 + lg) ^ (q & 7)) << 4);
                bf16x8 pb = *(const bf16x8*)((const char*)&P_l[wid][0] + pba);
#pragma unroll
                for (int d = 0; d < 4; ++d) {
                    int row = d * 16 + q;
                    int addr = row * 128 + (((kk2 * 4 + lg) ^ (row & 7)) << 4);
                    bf16x8 va = *(const bf16x8*)((const char*)&V_l[cur][0] + addr);
                    acc[d] = __builtin_amdgcn_mfma_f32_16x16x32_bf16(va, pb, acc[d], 0, 0, 0);
                }
            }
        }
        __syncthreads();                                 // all 8 waves, every iter
        cur ^= 1;
    }
#undef STAGE

    float inv = 1.f / lsum;
#pragma unroll
    for (int d = 0; d < 4; ++d) {
        short4v o4 = { f2bf(acc[d][0] * inv), f2bf(acc[d][1] * inv),
                       f2bf(acc[d][2] * inv), f2bf(acc[d][3] * inv) };
        *(short4v*)(Ob + ((size_t)(b * S_ + qrow) * H_ + h) * HD_ + d * 16 + lg * 4) = o4;
    }
}

extern "C" void kernel_launch(void* const* d_in, const int* in_sizes, int n_in,
                              void* d_out, int out_size, void* d_ws, size_t ws_size,
                              hipStream_t stream)
{
    const float* x  = (const float*)d_in[0];
    const float* wq = (const float*)d_in[1];
    const float* wk = (const float*)d_in[2];
    const float* wv = (const float*)d_in[3];
    const float* wo = (const float*)d_in[4];
    const float* fc = (const float*)d_in[5];
    const float* fs = (const float*)d_in[6];
    float* out = (float*)d_out;

    char* ws = (char*)d_ws;
    short* wqkvb = (short*)(ws);                  // 1536*1024 bf16  3.0 MB
    short* wob   = (short*)(ws + 3145728);        // 1024*1024 bf16  2.0 MB
    short* xb    = (short*)(ws + 5242880);        // 4096*1024 bf16  8.0 MB
    short* qb    = (short*)(ws + 13631488);       // [b][s][16][64]  8.0 MB
    short* kb    = (short*)(ws + 22020096);       // [b][s][4][64]   2.0 MB
    short* vb    = (short*)(ws + 24117248);       // [b][s][4][64]   2.0 MB
    short* vtb   = (short*)(ws + 26214400);       // [b][4][64][S]   2.0 MB
    short* aob   = xb;                            // alias: x dead after QKV GEMM

    cast_all<<<6656, 256, 0, stream>>>(x, wq, wk, wv, wo, xb, wqkvb, wob);

    gemm_qkv<<<dim3(12, 32), 256, 0, stream>>>(xb, wqkvb, fc, fs, qb, kb, vb);

    transpose_v<<<dim3(32, 4, 2), 256, 0, stream>>>(vb, vtb);

    attn_mfma<<<dim3(16, 16, 2), 512, 0, stream>>>(qb, kb, vtb, aob);

    gemm_bf16_nt<<<dim3(8, 32), 256, 0, stream>>>(aob, wob, out, 1024, 1024);
}

// Round 15
// 193.269 us; speedup vs baseline: 1.1625x; 1.0184x over previous
//
#include <hip/hip_runtime.h>
#include <hip/hip_bf16.h>

// R15 = R14 + attention VALU cuts: native bf16 cvt (v_cvt_pk), tree max/sum,
// s_setprio around MFMA clusters. Structure identical to R14 (196.8 us,
// attn 51.0 @ VALU 39%/Mfma 13%/Occ 33%).
// B=2 S=2048 D=1024 H=16 HKV=4 HD=64 REP=4

#define B_   2
#define S_   2048
#define D_   1024
#define H_   16
#define HKV_ 4
#define HD_  64

typedef __attribute__((ext_vector_type(8))) short bf16x8;
typedef __attribute__((ext_vector_type(4))) float f32x4;
typedef __attribute__((ext_vector_type(4))) short short4v;

__device__ __forceinline__ short f2bf(float f) {
    return __builtin_bit_cast(short, __float2bfloat16(f));   // native cvt (RNE)
}

__device__ __forceinline__ void gll16(const void* g, void* l) {
    __builtin_amdgcn_global_load_lds(
        (const __attribute__((address_space(1))) unsigned int*)g,
        (__attribute__((address_space(3))) unsigned int*)l, 16, 0, 0);
}

// ---------------- merged cast: x|wq|wk|wv|wo -> xb | wqkvb(wq|wk|wv) | wob ----------------
__global__ void cast_all(const float* __restrict__ x,  const float* __restrict__ wq,
                         const float* __restrict__ wk, const float* __restrict__ wv,
                         const float* __restrict__ wo,
                         short* __restrict__ xb, short* __restrict__ wqkvb,
                         short* __restrict__ wob) {
    int i4 = blockIdx.x * blockDim.x + threadIdx.x;
    const float* src;
    short* dst;
    int base;
    if (i4 < 1048576)      { src = x;  dst = xb;    base = 0; }
    else if (i4 < 1310720) { src = wq; dst = wqkvb; base = 1048576; }
    else if (i4 < 1376256) { src = wk; dst = wqkvb + 1048576; base = 1310720; }
    else if (i4 < 1441792) { src = wv; dst = wqkvb + 1310720; base = 1376256; }
    else                   { src = wo; dst = wob;   base = 1441792; }
    int e = (i4 - base) * 4;
    float4 v = *(const float4*)(src + e);
    short4v o = { f2bf(v.x), f2bf(v.y), f2bf(v.z), f2bf(v.w) };
    *(short4v*)(dst + e) = o;
}

// ---------------- QKV GEMM + fused rope/scale/cast epilogue ----------------
__global__ __launch_bounds__(256, 2) void gemm_qkv(
    const short* __restrict__ A, const short* __restrict__ W,
    const float* __restrict__ fc, const float* __restrict__ fs,
    short* __restrict__ qb, short* __restrict__ kb, short* __restrict__ vb) {
    __shared__ short A_l[128 * 64];
    __shared__ short B_l[128 * 64];
    const int t = threadIdx.x, ln = t & 63, wid = t >> 6;
    const int wr = wid >> 1, wc = wid & 1;
    const int r0 = blockIdx.y * 128, c0 = blockIdx.x * 128;
    const int K = 1024;
    f32x4 acc[4][4] = {};
    for (int k0 = 0; k0 < K; k0 += 64) {
#pragma unroll
        for (int i = 0; i < 4; ++i) {
            int row = wid * 32 + i * 8 + (ln >> 3);
            int sc_ = ((ln & 7) ^ (row & 7)) * 8;
            gll16(A + (size_t)(r0 + row) * K + k0 + sc_, A_l + wid * 2048 + i * 512);
            gll16(W + (size_t)(c0 + row) * K + k0 + sc_, B_l + wid * 2048 + i * 512);
        }
        __syncthreads();
#pragma unroll
        for (int kk = 0; kk < 2; ++kk) {
            bf16x8 af[4], bfr[4];
#pragma unroll
            for (int mi = 0; mi < 4; ++mi) {
                int row = wr * 64 + mi * 16 + (ln & 15);
                int addr = row * 128 + (((kk * 4 + (ln >> 4)) ^ (row & 7)) << 4);
                af[mi] = *(const bf16x8*)((const char*)A_l + addr);
            }
#pragma unroll
            for (int ni = 0; ni < 4; ++ni) {
                int col = wc * 64 + ni * 16 + (ln & 15);
                int addr = col * 128 + (((kk * 4 + (ln >> 4)) ^ (col & 7)) << 4);
                bfr[ni] = *(const bf16x8*)((const char*)B_l + addr);
            }
#pragma unroll
            for (int mi = 0; mi < 4; ++mi)
#pragma unroll
                for (int ni = 0; ni < 4; ++ni)
                    acc[mi][ni] = __builtin_amdgcn_mfma_f32_16x16x32_bf16(
                        af[mi], bfr[ni], acc[mi][ni], 0, 0, 0);
        }
        __syncthreads();
    }

    const float QSCALE = 0.18033688f;     // 0.125 * log2(e)
    const int region = (c0 < 1024) ? 0 : (c0 < 1280 ? 1 : 2);   // block-uniform
#pragma unroll
    for (int mi = 0; mi < 4; ++mi)
#pragma unroll
        for (int ni = 0; ni < 4; ++ni) {
            int col = c0 + wc * 64 + ni * 16 + (ln & 15);
#pragma unroll
            for (int rg = 0; rg < 4; ++rg) {
                int row = r0 + wr * 64 + mi * 16 + (ln >> 4) * 4 + rg;
                int s = row & (S_ - 1), b = row >> 11;
                float v = acc[mi][ni][rg];
                if (region == 2) {                       // V: plain cast
                    int cc = col - 1280, g = cc >> 6, d = cc & 63;
                    vb[((size_t)(b * S_ + s) * HKV_ + g) * HD_ + d] = f2bf(v);
                } else {                                 // Q/K: rope
                    int cc = region ? (col - 1024) : col;
                    int d = cc & 63, p = d >> 1;
                    float c = fc[s * 32 + p], sn = fs[s * 32 + p];
                    float pv = __shfl_xor(v, 1);
                    float sgn = (col & 1) ? sn : -sn;
                    float o = v * c + sgn * pv;
                    if (region == 0) {
                        o *= QSCALE;
                        qb[((size_t)(b * S_ + s) * H_ + (cc >> 6)) * HD_ + d] = f2bf(o);
                    } else {
                        kb[((size_t)(b * S_ + s) * HKV_ + (cc >> 6)) * HD_ + d] = f2bf(o);
                    }
                }
            }
        }
}

// ---------------- V transpose: [b][s][g][64] bf16 -> [b][g][64][S] bf16 ----------------
__global__ __launch_bounds__(256) void transpose_v(const short* __restrict__ vb,
                                                   short* __restrict__ vt) {
    __shared__ short tl[64][68];          // 68: 8B-aligned rows + bank-break
    const int t = threadIdx.x;
    const int s0 = blockIdx.x * 64, g = blockIdx.y, b = blockIdx.z;
#pragma unroll
    for (int i = 0; i < 4; ++i) {
        int e = t + i * 256, r = e >> 4, c4 = (e & 15) * 4;
        *(short4v*)&tl[r][c4] =
            *(const short4v*)(vb + ((size_t)(b * S_ + s0 + r) * HKV_ + g) * HD_ + c4);
    }
    __syncthreads();
    const int dr = t >> 2, sc0 = (t & 3) * 16;
#pragma unroll
    for (int i = 0; i < 4; ++i) {
        short4v o = { tl[sc0 + i * 4 + 0][dr], tl[sc0 + i * 4 + 1][dr],
                      tl[sc0 + i * 4 + 2][dr], tl[sc0 + i * 4 + 3][dr] };
        *(short4v*)(vt + ((size_t)((b * HKV_ + g) * 64 + dr)) * S_ + s0 + sc0 + i * 4) = o;
    }
}

// ---------------- WO GEMM (bf16 in, fp32 out) ----------------
__global__ __launch_bounds__(256, 2) void gemm_bf16_nt(
    const short* __restrict__ A, const short* __restrict__ Bw,
    float* __restrict__ C, int N, int K) {
    __shared__ short A_l[128 * 64];
    __shared__ short B_l[128 * 64];
    const int t = threadIdx.x, ln = t & 63, wid = t >> 6;
    const int wr = wid >> 1, wc = wid & 1;
    const int r0 = blockIdx.y * 128, c0 = blockIdx.x * 128;
    f32x4 acc[4][4] = {};
    for (int k0 = 0; k0 < K; k0 += 64) {
#pragma unroll
        for (int i = 0; i < 4; ++i) {
            int row = wid * 32 + i * 8 + (ln >> 3);
            int sc_ = ((ln & 7) ^ (row & 7)) * 8;
            gll16(A + (size_t)(r0 + row) * K + k0 + sc_, A_l + wid * 2048 + i * 512);
            gll16(Bw + (size_t)(c0 + row) * K + k0 + sc_, B_l + wid * 2048 + i * 512);
        }
        __syncthreads();
#pragma unroll
        for (int kk = 0; kk < 2; ++kk) {
            bf16x8 af[4], bfr[4];
#pragma unroll
            for (int mi = 0; mi < 4; ++mi) {
                int row = wr * 64 + mi * 16 + (ln & 15);
                int addr = row * 128 + (((kk * 4 + (ln >> 4)) ^ (row & 7)) << 4);
                af[mi] = *(const bf16x8*)((const char*)A_l + addr);
            }
#pragma unroll
            for (int ni = 0; ni < 4; ++ni) {
                int col = wc * 64 + ni * 16 + (ln & 15);
                int addr = col * 128 + (((kk * 4 + (ln >> 4)) ^ (col & 7)) << 4);
                bfr[ni] = *(const bf16x8*)((const char*)B_l + addr);
            }
#pragma unroll
            for (int mi = 0; mi < 4; ++mi)
#pragma unroll
                for (int ni = 0; ni < 4; ++ni)
                    acc[mi][ni] = __builtin_amdgcn_mfma_f32_16x16x32_bf16(
                        af[mi], bfr[ni], acc[mi][ni], 0, 0, 0);
        }
        __syncthreads();
    }
#pragma unroll
    for (int mi = 0; mi < 4; ++mi)
#pragma unroll
        for (int ni = 0; ni < 4; ++ni)
#pragma unroll
            for (int rg = 0; rg < 4; ++rg) {
                int r = r0 + wr * 64 + mi * 16 + (ln >> 4) * 4 + rg;
                int c = c0 + wc * 64 + ni * 16 + (ln & 15);
                C[(size_t)r * N + c] = acc[mi][ni][rg];
            }
}

// ---------------- flash-causal GQA attention, PAIRED q-tiles ----------------
// Block = (pair jp, head, batch), 8 waves / 512 threads. Uniform 33 steps.
// R15: tree max/sum, native cvt_pk bf16 pack, setprio around MFMA.
__global__ __launch_bounds__(512, 4) void attn_mfma(
    const short* __restrict__ Qb, const short* __restrict__ Kb,
    const short* __restrict__ Vt, short* __restrict__ Ob) {
    __shared__ short K_l[2][64 * 64];
    __shared__ short V_l[2][64 * 64];
    __shared__ short P_l[8][16 * 64];
    const int t = threadIdx.x, ln = t & 63, wid = t >> 6;   // wid 0..7
    const int jp = blockIdx.x;                              // 0..15
    const int h = blockIdx.y, b = blockIdx.z, g = h >> 2;
    const int half = wid >> 2;                              // 0: qt=jp, 1: qt=31-jp
    const int wl = wid & 3;
    const int myqt = half ? (31 - jp) : jp;
    const int qtB = 31 - jp;                                // loop bound (>= myqt)
    const int q0 = myqt * 64;
    const int lg = ln >> 4, q = ln & 15;
    const int qrow = q0 + wl * 16 + q;
    const int stg_row = wl * 16 + (ln >> 3);                // 16 rows per wave
    const int stg_sc0 = (ln & 7) * 8;

    bf16x8 qf[2];
#pragma unroll
    for (int kk = 0; kk < 2; ++kk)
        qf[kk] = *(const bf16x8*)(Qb + ((size_t)(b * S_ + qrow) * H_ + h) * HD_ + kk * 32 + lg * 8);

    f32x4 acc[4] = {};
    float mrun = -3.0e38f, lsum = 0.f;

#define STAGE(KT, BUF)                                                              \
    {                                                                               \
        const int k0s = (KT) * 64;                                                  \
        _Pragma("unroll")                                                           \
        for (int i = 0; i < 2; ++i) {                                               \
            int row = stg_row + i * 8;                                              \
            int sc_ = stg_sc0 ^ ((row & 7) * 8);                                    \
            if (half == 0)                                                          \
                gll16(Kb + ((size_t)(b * S_ + k0s + row) * HKV_ + g) * HD_ + sc_,   \
                      &K_l[BUF][wl * 1024 + i * 512]);                              \
            else                                                                    \
                gll16(Vt + ((size_t)((b * HKV_ + g) * 64 + row)) * S_ + k0s + sc_,  \
                      &V_l[BUF][wl * 1024 + i * 512]);                              \
        }                                                                           \
    }

    STAGE(0, 0);
    __syncthreads();
    int cur = 0;

    for (int kt = 0; kt <= qtB; ++kt) {
        if (kt < qtB) STAGE(kt + 1, cur ^ 1);

        if (kt <= myqt) {                                   // wave-uniform
            const int k0 = kt * 64;
            f32x4 st[4] = {};
            __builtin_amdgcn_s_setprio(1);
#pragma unroll
            for (int kk = 0; kk < 2; ++kk)
#pragma unroll
                for (int r = 0; r < 4; ++r) {
                    int row = r * 16 + q;
                    int addr = row * 128 + (((kk * 4 + lg) ^ (row & 7)) << 4);
                    bf16x8 ka = *(const bf16x8*)((const char*)&K_l[cur][0] + addr);
                    st[r] = __builtin_amdgcn_mfma_f32_16x16x32_bf16(ka, qf[kk], st[r], 0, 0, 0);
                }
            __builtin_amdgcn_s_setprio(0);

            const bool diag = (kt == myqt);
            if (diag) {
#pragma unroll
                for (int r = 0; r < 4; ++r)
#pragma unroll
                    for (int j = 0; j < 4; ++j)
                        if (k0 + r * 16 + lg * 4 + j > qrow) st[r][j] = -3.0e38f;
            }
            float mr[4];
#pragma unroll
            for (int r = 0; r < 4; ++r)
                mr[r] = fmaxf(fmaxf(st[r][0], st[r][1]), fmaxf(st[r][2], st[r][3]));
            float mloc = fmaxf(fmaxf(mr[0], mr[1]), fmaxf(mr[2], mr[3]));
            mloc = fmaxf(mloc, __shfl_xor(mloc, 16));
            mloc = fmaxf(mloc, __shfl_xor(mloc, 32));

            if (!__all(mloc <= mrun + 8.f)) {               // defer-max (T13)
                float nm = fmaxf(mrun, mloc);
                float scl = __builtin_amdgcn_exp2f(mrun - nm);
                lsum *= scl;
#pragma unroll
                for (int d = 0; d < 4; ++d)
#pragma unroll
                    for (int j = 0; j < 4; ++j) acc[d][j] *= scl;
                mrun = nm;
            }

            float sr[4];
#pragma unroll
            for (int r = 0; r < 4; ++r) {
#pragma unroll
                for (int j = 0; j < 4; ++j)
                    st[r][j] = __builtin_amdgcn_exp2f(st[r][j] - mrun);
                sr[r] = (st[r][0] + st[r][1]) + (st[r][2] + st[r][3]);
            }
            float rsum = (sr[0] + sr[1]) + (sr[2] + sr[3]);
            rsum += __shfl_xor(rsum, 16);
            rsum += __shfl_xor(rsum, 32);
            lsum += rsum;

#pragma unroll
            for (int r = 0; r < 4; ++r) {
                short4v pk = { f2bf(st[r][0]), f2bf(st[r][1]), f2bf(st[r][2]), f2bf(st[r][3]) };
                int sb = q * 128 + ((r * 32 + lg * 8) ^ ((q & 7) << 4));
                *(short4v*)((char*)&P_l[wid][0] + sb) = pk;
            }

            __builtin_amdgcn_s_setprio(1);
#pragma unroll
            for (int kk2 = 0; kk2 < 2; ++kk2) {
                int pba = q * 128 + (((kk2 * 4 + lg) ^ (q & 7)) << 4);
                bf16x8 pb = *(const bf16x8*)((const char*)&P_l[wid][0] + pba);
#pragma unroll
                for (int d = 0; d < 4; ++d) {
                    int row = d * 16 + q;
                    int addr = row * 128 + (((kk2 * 4 + lg) ^ (row & 7)) << 4);
                    bf16x8 va = *(const bf16x8*)((const char*)&V_l[cur][0] + addr);
                    acc[d] = __builtin_amdgcn_mfma_f32_16x16x32_bf16(va, pb, acc[d], 0, 0, 0);
                }
            }
            __builtin_amdgcn_s_setprio(0);
        }
        __syncthreads();                                 // all 8 waves, every iter
        cur ^= 1;
    }
#undef STAGE

    float inv = 1.f / lsum;
#pragma unroll
    for (int d = 0; d < 4; ++d) {
        short4v o4 = { f2bf(acc[d][0] * inv), f2bf(acc[d][1] * inv),
                       f2bf(acc[d][2] * inv), f2bf(acc[d][3] * inv) };
        *(short4v*)(Ob + ((size_t)(b * S_ + qrow) * H_ + h) * HD_ + d * 16 + lg * 4) = o4;
    }
}

extern "C" void kernel_launch(void* const* d_in, const int* in_sizes, int n_in,
                              void* d_out, int out_size, void* d_ws, size_t ws_size,
                              hipStream_t stream)
{
    const float* x  = (const float*)d_in[0];
    const float* wq = (const float*)d_in[1];
    const float* wk = (const float*)d_in[2];
    const float* wv = (const float*)d_in[3];
    const float* wo = (const float*)d_in[4];
    const float* fc = (const float*)d_in[5];
    const float* fs = (const float*)d_in[6];
    float* out = (float*)d_out;

    char* ws = (char*)d_ws;
    short* wqkvb = (short*)(ws);                  // 1536*1024 bf16  3.0 MB
    short* wob   = (short*)(ws + 3145728);        // 1024*1024 bf16  2.0 MB
    short* xb    = (short*)(ws + 5242880);        // 4096*1024 bf16  8.0 MB
    short* qb    = (short*)(ws + 13631488);       // [b][s][16][64]  8.0 MB
    short* kb    = (short*)(ws + 22020096);       // [b][s][4][64]   2.0 MB
    short* vb    = (short*)(ws + 24117248);       // [b][s][4][64]   2.0 MB
    short* vtb   = (short*)(ws + 26214400);       // [b][4][64][S]   2.0 MB
    short* aob   = xb;                            // alias: x dead after QKV GEMM

    cast_all<<<6656, 256, 0, stream>>>(x, wq, wk, wv, wo, xb, wqkvb, wob);

    gemm_qkv<<<dim3(12, 32), 256, 0, stream>>>(xb, wqkvb, fc, fs, qb, kb, vb);

    transpose_v<<<dim3(32, 4, 2), 256, 0, stream>>>(vb, vtb);

    attn_mfma<<<dim3(16, 16, 2), 512, 0, stream>>>(qb, kb, vtb, aob);

    gemm_bf16_nt<<<dim3(8, 32), 256, 0, stream>>>(aob, wob, out, 1024, 1024);
}